// Round 2
// 1613.012 us; speedup vs baseline: 1.1720x; 1.1720x over previous
//
#include <hip/hip_runtime.h>
#include <hip/hip_bf16.h>

typedef unsigned short u16;
typedef unsigned int   u32;
typedef __attribute__((ext_vector_type(8))) __bf16 bf16x8;
typedef __attribute__((ext_vector_type(4))) float  f32x4;

#define NWIN   4096
#define SEQ    64
#define DIMC   384
#define NHEAD  12
#define HDIM   32
#define NROWS  262144      /* NWIN*SEQ */
#define NQKV   1152

__device__ __forceinline__ u16 f2bf(float f){
  u32 x = __float_as_uint(f);
  return (u16)((x + 0x7fffu + ((x >> 16) & 1u)) >> 16);   // RNE
}

__device__ __forceinline__ void gload_lds16(const u16* g, u16* l){
  __builtin_amdgcn_global_load_lds(
      (const __attribute__((address_space(1))) void*)g,
      (__attribute__((address_space(3))) void*)l, 16, 0, 0);
}

__device__ __forceinline__ f32x4 mfma_bf16(bf16x8 a, bf16x8 b, f32x4 c){
  return __builtin_amdgcn_mfma_f32_16x16x32_bf16(a, b, c, 0, 0, 0);
}

// ---------------- prep kernels ----------------
__global__ void prep_x(const float* __restrict__ x, u16* __restrict__ xb){
  size_t i = ((size_t)blockIdx.x * 256 + threadIdx.x) * 8;
  f32x4 a = *(const f32x4*)(x + i);
  f32x4 b = *(const f32x4*)(x + i + 4);
  union { u16 u[8]; bf16x8 v; } o;
  #pragma unroll
  for(int j=0;j<4;j++) o.u[j]   = f2bf(a[j]);
  #pragma unroll
  for(int j=0;j<4;j++) o.u[4+j] = f2bf(b[j]);
  *(bf16x8*)(xb + i) = o.v;
}

// transpose+convert weights, build biasT[h][n][m]
__global__ void prep_w(const float* __restrict__ qw, const float* __restrict__ pw,
                       const float* __restrict__ rpb, const int* __restrict__ rpi,
                       u16* __restrict__ wqT, u16* __restrict__ wpT,
                       float* __restrict__ biasT){
  int id = blockIdx.x * 256 + threadIdx.x;
  if (id < NQKV*DIMC){                      // qkv_wT[n][k] = qkv_w[k][n]
    int n = id / DIMC, k = id % DIMC;
    wqT[id] = f2bf(qw[(size_t)k*NQKV + n]);
  } else if (id < NQKV*DIMC + DIMC*DIMC){   // projT[n][k] = proj_w[k][n]
    int j = id - NQKV*DIMC;
    int n = j / DIMC, k = j % DIMC;
    wpT[j] = f2bf(pw[(size_t)k*DIMC + n]);
  } else {
    int j = id - (NQKV*DIMC + DIMC*DIMC);   // 0 .. 12*4096-1
    int h = j / 4096, nm = j % 4096;
    biasT[j] = rpb[rpi[nm]*NHEAD + h];
  }
}

// ---------------- GEMM: C[M x 128NB..] = A[M x 384] * Bt[N x 384]^T + bias ----------------
// EPI=0: bf16 out split into q/k/v regions.  EPI=1: fp32 out.
template<int NB, int EPI>
__global__ __launch_bounds__(256, 2) void gemm_bt(
    const u16* __restrict__ A, const u16* __restrict__ Bt,
    const float* __restrict__ bias,
    u16* __restrict__ oq, u16* __restrict__ okk, u16* __restrict__ ov,
    float* __restrict__ of)
{
  // tiles [128 rows][64 k] bf16, 16B-unit XOR swizzle: phys_u = u ^ (row&7)
  __shared__ u16 Al[2][8192];
  __shared__ u16 Bl[2][8192];
  const int bid = blockIdx.x;
  const int bm = bid / NB, bn = bid % NB;
  const size_t m0 = (size_t)bm * 128;
  const int n0 = bn * 128;
  const int tid = threadIdx.x, wv = tid >> 6, ln = tid & 63;
  const int wr = wv >> 1, wc = wv & 1;         // 2x2 waves, 64x64 per wave
  const int cl = ln & 15, q8 = ln >> 4;

  f32x4 acc[4][4];
  const f32x4 zero4 = {0.f,0.f,0.f,0.f};
  #pragma unroll
  for(int i=0;i<4;i++)
    #pragma unroll
    for(int j=0;j<4;j++) acc[i][j] = zero4;

  auto stage = [&](int bufi, int kt){
    #pragma unroll
    for(int c=0;c<4;c++){
      int un  = (wv*4+c)*64 + ln;        // linear 16B-unit index 0..1023
      int row = un >> 3;
      int u   = (un & 7) ^ (row & 7);    // logical unit stored at this phys slot
      gload_lds16(A  + (m0 + row)*DIMC + kt*64 + u*8, &Al[bufi][(wv*4+c)*512]);
      gload_lds16(Bt + (size_t)(n0 + row)*DIMC + kt*64 + u*8, &Bl[bufi][(wv*4+c)*512]);
    }
  };

  stage(0, 0);
  #pragma unroll
  for(int kt=0;kt<6;kt++){
    const int bufi = kt & 1;
    __syncthreads();                     // drains in-flight global_load_lds
    if (kt < 5) stage(bufi^1, kt+1);     // prefetch next tile into other buffer
    #pragma unroll
    for(int ks=0;ks<2;ks++){
      bf16x8 af[4], bfr[4];
      #pragma unroll
      for(int i=0;i<4;i++){
        int row = wr*64 + i*16 + cl;
        int u = (ks*4 + q8) ^ (row & 7);
        af[i] = *(const bf16x8*)&Al[bufi][row*64 + u*8];
      }
      #pragma unroll
      for(int j=0;j<4;j++){
        int row = wc*64 + j*16 + cl;
        int u = (ks*4 + q8) ^ (row & 7);
        bfr[j] = *(const bf16x8*)&Bl[bufi][row*64 + u*8];
      }
      #pragma unroll
      for(int i=0;i<4;i++)
        #pragma unroll
        for(int j=0;j<4;j++)
          acc[i][j] = mfma_bf16(af[i], bfr[j], acc[i][j]);
    }
  }

  float bj[4];
  #pragma unroll
  for(int j=0;j<4;j++) bj[j] = bias[n0 + wc*64 + j*16 + cl];

  if (EPI == 0){
    const int t = n0 / DIMC;                       // 0:q 1:k 2:v (128 | 384)
    const int lc0 = n0 - t*DIMC + wc*64 + cl;
    u16* dst = (t==0) ? oq : (t==1) ? okk : ov;
    #pragma unroll
    for(int i=0;i<4;i++){
      size_t r0 = m0 + wr*64 + i*16 + q8*4;
      #pragma unroll
      for(int j=0;j<4;j++)
        #pragma unroll
        for(int r=0;r<4;r++)
          dst[(r0 + r)*DIMC + lc0 + j*16] = f2bf(acc[i][j][r] + bj[j]);
    }
  } else {
    const int lc0 = n0 + wc*64 + cl;
    #pragma unroll
    for(int i=0;i<4;i++){
      size_t r0 = m0 + wr*64 + i*16 + q8*4;
      #pragma unroll
      for(int j=0;j<4;j++)
        #pragma unroll
        for(int r=0;r<4;r++)
          of[(r0 + r)*DIMC + lc0 + j*16] = acc[i][j][r] + bj[j];
    }
  }
}

// ---------------- fused window attention ----------------
// 1 block = (window, 4-head group), 4 waves, wave handles 1 head.
// LDS 48KB/block -> 3 blocks/CU (12 waves/CU) vs old 147KB (1 block, 4 waves).
// bid -> w = bid/3 so the 3 blocks sharing a window's mask launch adjacently
// (same-XCD L2 absorbs the 3x mask re-read).
__global__ __launch_bounds__(256, 3) void attn_win(
    const u16* __restrict__ Q, const u16* __restrict__ K, const u16* __restrict__ V,
    const float* __restrict__ biasT, const float* __restrict__ mask,
    u16* __restrict__ AO)
{
  // per head: [q 64x32 | k 64x32] (4096 u16) -- later overlaid by P [64x64] (swizzled)
  __shared__ u16 qk[4][4096];
  __shared__ u16 vt[4][2048];   // vT [32 dims][64 toks] (swizzled rows of 128B)
  const int bid = blockIdx.x;
  const int w  = bid / 3, hg = bid % 3;
  const int tid = threadIdx.x, wv = tid >> 6, ln = tid & 63;
  const int cl = ln & 15, g = ln >> 4;
  const size_t rb = (size_t)w * SEQ;
  const int h0 = hg * 4;
  const f32x4 zero4 = {0.f,0.f,0.f,0.f};

  // stage Q,K for this head group: each wave stages its own head (4x 1KB DMA each)
  #pragma unroll
  for(int c=0;c<4;c++){
    int f = wv*4 + c;                  // 0..15
    int hl = f >> 2, i = f & 3;        // hl == wv
    size_t src = (rb + i*16 + (ln>>2))*DIMC + (h0+hl)*HDIM + (ln&3)*8;
    gload_lds16(Q + src, &qk[hl][i*512]);
    gload_lds16(K + src, &qk[hl][2048 + i*512]);
  }
  // stage V transposed (manual), 4 heads = 64 toks x 128 dims
  #pragma unroll
  for(int c=0;c<4;c++){
    int ch = c*256 + tid;              // 0..1023 chunks of 8 dims
    int tok = ch >> 4, dc = ch & 15;
    union { bf16x8 v; u16 u[8]; } vv;
    vv.v = *(const bf16x8*)(V + (rb + tok)*DIMC + h0*HDIM + dc*8);
    #pragma unroll
    for(int j=0;j<8;j++){
      int d = dc*8 + j, hl = d >> 5, dh = d & 31;
      vt[hl][dh*64 + (((tok>>3) ^ (dh&7)) * 8) + (tok & 7)] = vv.u[j];
    }
  }
  __syncthreads();

  const float scale = 0.17677669529663687f;   // 32^-0.5
  const int h = h0 + wv;
  u16* ph = qk[wv];
  const u16* pv = vt[wv];

  bf16x8 aq[4], bk[4];
  #pragma unroll
  for(int i=0;i<4;i++) aq[i] = *(const bf16x8*)&ph[(i*16 + cl)*32 + g*8];
  #pragma unroll
  for(int j=0;j<4;j++) bk[j] = *(const bf16x8*)&ph[2048 + (j*16 + cl)*32 + g*8];
  f32x4 S[4][4];
  #pragma unroll
  for(int i=0;i<4;i++)
    #pragma unroll
    for(int j=0;j<4;j++)
      S[i][j] = mfma_bf16(aq[i], bk[j], zero4);   // K=32: one k-step

  float l[4][4];
  #pragma unroll
  for(int i=0;i<4;i++){
    #pragma unroll
    for(int r=0;r<4;r++){
      int row = i*16 + g*4 + r;
      float v0[4];
      #pragma unroll
      for(int j=0;j<4;j++){
        int col2 = j*16 + cl;
        v0[j] = S[i][j][r]*scale + biasT[h*4096 + row*64 + col2]
                                 + mask[(size_t)w*4096 + row*64 + col2];
      }
      float mx = fmaxf(fmaxf(v0[0],v0[1]), fmaxf(v0[2],v0[3]));
      #pragma unroll
      for(int s=1;s<16;s<<=1) mx = fmaxf(mx, __shfl_xor(mx, s));
      float sm = 0.f;
      #pragma unroll
      for(int j=0;j<4;j++){ v0[j] = __expf(v0[j]-mx); sm += v0[j]; }
      #pragma unroll
      for(int s=1;s<16;s<<=1) sm += __shfl_xor(sm, s);
      l[i][r] = sm;
      // P (unnormalized) -> LDS over q|k slot, A-layout rows of 64 cols, swizzled
      #pragma unroll
      for(int j=0;j<4;j++){
        int col2 = j*16 + cl;
        ph[row*64 + (((col2>>3) ^ (row&7))*8) + (col2&7)] = f2bf(v0[j]);
      }
    }
  }
  // O = P @ V  (64x64 @ 64x32, 2 k-steps)
  f32x4 O[4][2];
  #pragma unroll
  for(int i=0;i<4;i++){ O[i][0] = zero4; O[i][1] = zero4; }
  #pragma unroll
  for(int ks=0;ks<2;ks++){
    bf16x8 ap[4], bv[2];
    #pragma unroll
    for(int i=0;i<4;i++){
      int m = i*16 + cl;
      ap[i] = *(const bf16x8*)&ph[m*64 + (((ks*4+g) ^ (m&7))*8)];
    }
    #pragma unroll
    for(int j=0;j<2;j++){
      int n = j*16 + cl;
      bv[j] = *(const bf16x8*)&pv[n*64 + (((ks*4+g) ^ (n&7))*8)];
    }
    #pragma unroll
    for(int i=0;i<4;i++)
      #pragma unroll
      for(int j=0;j<2;j++)
        O[i][j] = mfma_bf16(ap[i], bv[j], O[i][j]);
  }
  #pragma unroll
  for(int i=0;i<4;i++){
    #pragma unroll
    for(int r=0;r<4;r++){
      float inv = 1.0f / l[i][r];
      size_t orow = (rb + i*16 + g*4 + r)*DIMC + h*HDIM;
      AO[orow + cl]      = f2bf(O[i][0][r]*inv);
      AO[orow + 16 + cl] = f2bf(O[i][1][r]*inv);
    }
  }
}

// ---------------- launch ----------------
extern "C" void kernel_launch(void* const* d_in, const int* in_sizes, int n_in,
                              void* d_out, int out_size, void* d_ws, size_t ws_size,
                              hipStream_t stream) {
  const float* x      = (const float*)d_in[0];
  const float* mask   = (const float*)d_in[1];
  const float* qkv_w  = (const float*)d_in[2];
  const float* qkv_b  = (const float*)d_in[3];
  const float* rpb    = (const float*)d_in[4];
  const float* proj_w = (const float*)d_in[5];
  const float* proj_b = (const float*)d_in[6];
  const int*   rpi    = (const int*)d_in[7];

  // ws layout (u16 units): [x_bf16 | v_bf16 | wqT | wpT] then biasT (f32)
  u16* xb  = (u16*)d_ws;                        // NROWS*DIMC, reused as attn-out
  u16* vb  = xb + (size_t)NROWS*DIMC;
  u16* wqT = vb + (size_t)NROWS*DIMC;
  u16* wpT = wqT + (size_t)NQKV*DIMC;
  float* biasT = (float*)(wpT + (size_t)DIMC*DIMC);
  u16* qb = (u16*)d_out;                        // Q,K live in d_out until final GEMM
  u16* kb = qb + (size_t)NROWS*DIMC;
  u16* ao = xb;                                 // attn-out reuses x_bf16 region

  prep_x<<<(NROWS*(size_t)DIMC)/(256*8), 256, 0, stream>>>(x, xb);
  prep_w<<<(NQKV*DIMC + DIMC*DIMC + NHEAD*4096)/256, 256, 0, stream>>>(
      qkv_w, proj_w, rpb, rpi, wqT, wpT, biasT);
  gemm_bt<9,0><<<2048*9, 256, 0, stream>>>(xb, wqT, qkv_b, qb, kb, vb, nullptr);
  attn_win<<<NWIN*3, 256, 0, stream>>>(qb, kb, vb, biasT, mask, ao);
  gemm_bt<3,1><<<2048*3, 256, 0, stream>>>(ao, wpT, proj_b, nullptr, nullptr, nullptr,
                                           (float*)d_out);
}

// Round 3
// 1607.903 us; speedup vs baseline: 1.1758x; 1.0032x over previous
//
#include <hip/hip_runtime.h>
#include <hip/hip_bf16.h>

typedef unsigned short u16;
typedef unsigned int   u32;
typedef __attribute__((ext_vector_type(8))) __bf16 bf16x8;
typedef __attribute__((ext_vector_type(4))) float  f32x4;

#define NWIN   4096
#define SEQ    64
#define DIMC   384
#define NHEAD  12
#define HDIM   32
#define NROWS  262144      /* NWIN*SEQ */
#define NQKV   1152

__device__ __forceinline__ u16 f2bf(float f){
  u32 x = __float_as_uint(f);
  return (u16)((x + 0x7fffu + ((x >> 16) & 1u)) >> 16);   // RNE
}

__device__ __forceinline__ void gload_lds16(const u16* g, u16* l){
  __builtin_amdgcn_global_load_lds(
      (const __attribute__((address_space(1))) void*)g,
      (__attribute__((address_space(3))) void*)l, 16, 0, 0);
}

__device__ __forceinline__ f32x4 mfma_bf16(bf16x8 a, bf16x8 b, f32x4 c){
  return __builtin_amdgcn_mfma_f32_16x16x32_bf16(a, b, c, 0, 0, 0);
}

// ---------------- prep kernels ----------------
__global__ void prep_x(const float* __restrict__ x, u16* __restrict__ xb){
  size_t i = ((size_t)blockIdx.x * 256 + threadIdx.x) * 8;
  f32x4 a = *(const f32x4*)(x + i);
  f32x4 b = *(const f32x4*)(x + i + 4);
  union { u16 u[8]; bf16x8 v; } o;
  #pragma unroll
  for(int j=0;j<4;j++) o.u[j]   = f2bf(a[j]);
  #pragma unroll
  for(int j=0;j<4;j++) o.u[4+j] = f2bf(b[j]);
  *(bf16x8*)(xb + i) = o.v;
}

// transpose+convert weights, build biasT[h][n][m]
__global__ void prep_w(const float* __restrict__ qw, const float* __restrict__ pw,
                       const float* __restrict__ rpb, const int* __restrict__ rpi,
                       u16* __restrict__ wqT, u16* __restrict__ wpT,
                       float* __restrict__ biasT){
  int id = blockIdx.x * 256 + threadIdx.x;
  if (id < NQKV*DIMC){                      // qkv_wT[n][k] = qkv_w[k][n]
    int n = id / DIMC, k = id % DIMC;
    wqT[id] = f2bf(qw[(size_t)k*NQKV + n]);
  } else if (id < NQKV*DIMC + DIMC*DIMC){   // projT[n][k] = proj_w[k][n]
    int j = id - NQKV*DIMC;
    int n = j / DIMC, k = j % DIMC;
    wpT[j] = f2bf(pw[(size_t)k*DIMC + n]);
  } else {
    int j = id - (NQKV*DIMC + DIMC*DIMC);   // 0 .. 12*4096-1
    int h = j / 4096, nm = j % 4096;
    biasT[j] = rpb[rpi[nm]*NHEAD + h];
  }
}

// ---------------- GEMM: C[M x 128NB..] = A[M x 384] * Bt[N x 384]^T + bias ----------------
// EPI=0: bf16 out split into q/k/v regions.  EPI=1: fp32 out.
template<int NB, int EPI>
__global__ __launch_bounds__(256, 2) void gemm_bt(
    const u16* __restrict__ A, const u16* __restrict__ Bt,
    const float* __restrict__ bias,
    u16* __restrict__ oq, u16* __restrict__ okk, u16* __restrict__ ov,
    float* __restrict__ of)
{
  // tiles [128 rows][64 k] bf16, 16B-unit XOR swizzle: phys_u = u ^ (row&7)
  __shared__ u16 Al[2][8192];
  __shared__ u16 Bl[2][8192];
  // XCD-chunked bijective swizzle: consecutive logical blocks share an XCD L2,
  // so the 3 bn-tiles re-reading one A-panel hit L2 instead of HBM.
  const int bid0 = blockIdx.x;
  const int bid = (bid0 & 7) * ((2048*NB) >> 3) + (bid0 >> 3);
  const int bm = bid / NB, bn = bid % NB;
  const size_t m0 = (size_t)bm * 128;
  const int n0 = bn * 128;
  const int tid = threadIdx.x, wv = tid >> 6, ln = tid & 63;
  const int wr = wv >> 1, wc = wv & 1;         // 2x2 waves, 64x64 per wave
  const int cl = ln & 15, q8 = ln >> 4;

  f32x4 acc[4][4];
  const f32x4 zero4 = {0.f,0.f,0.f,0.f};
  #pragma unroll
  for(int i=0;i<4;i++)
    #pragma unroll
    for(int j=0;j<4;j++) acc[i][j] = zero4;

  auto stage = [&](int bufi, int kt){
    #pragma unroll
    for(int c=0;c<4;c++){
      int un  = (wv*4+c)*64 + ln;        // linear 16B-unit index 0..1023
      int row = un >> 3;
      int u   = (un & 7) ^ (row & 7);    // logical unit stored at this phys slot
      gload_lds16(A  + (m0 + row)*DIMC + kt*64 + u*8, &Al[bufi][(wv*4+c)*512]);
      gload_lds16(Bt + (size_t)(n0 + row)*DIMC + kt*64 + u*8, &Bl[bufi][(wv*4+c)*512]);
    }
  };

  stage(0, 0);
  #pragma unroll
  for(int kt=0;kt<6;kt++){
    const int bufi = kt & 1;
    __syncthreads();                     // drains in-flight global_load_lds
    if (kt < 5) stage(bufi^1, kt+1);     // prefetch next tile into other buffer
    #pragma unroll
    for(int ks=0;ks<2;ks++){
      bf16x8 af[4], bfr[4];
      #pragma unroll
      for(int i=0;i<4;i++){
        int row = wr*64 + i*16 + cl;
        int u = (ks*4 + q8) ^ (row & 7);
        af[i] = *(const bf16x8*)&Al[bufi][row*64 + u*8];
      }
      #pragma unroll
      for(int j=0;j<4;j++){
        int row = wc*64 + j*16 + cl;
        int u = (ks*4 + q8) ^ (row & 7);
        bfr[j] = *(const bf16x8*)&Bl[bufi][row*64 + u*8];
      }
      #pragma unroll
      for(int i=0;i<4;i++)
        #pragma unroll
        for(int j=0;j<4;j++)
          acc[i][j] = mfma_bf16(af[i], bfr[j], acc[i][j]);
    }
  }

  float bj[4];
  #pragma unroll
  for(int j=0;j<4;j++) bj[j] = bias[n0 + wc*64 + j*16 + cl];

  if (EPI == 0){
    const int t = n0 / DIMC;                       // 0:q 1:k 2:v (128 | 384)
    const int lc0 = n0 - t*DIMC + wc*64 + cl;
    u16* dst = (t==0) ? oq : (t==1) ? okk : ov;
    #pragma unroll
    for(int i=0;i<4;i++){
      size_t r0 = m0 + wr*64 + i*16 + q8*4;
      #pragma unroll
      for(int j=0;j<4;j++)
        #pragma unroll
        for(int r=0;r<4;r++)
          dst[(r0 + r)*DIMC + lc0 + j*16] = f2bf(acc[i][j][r] + bj[j]);
    }
  } else {
    const int lc0 = n0 + wc*64 + cl;
    #pragma unroll
    for(int i=0;i<4;i++){
      size_t r0 = m0 + wr*64 + i*16 + q8*4;
      #pragma unroll
      for(int j=0;j<4;j++)
        #pragma unroll
        for(int r=0;r<4;r++)
          of[(r0 + r)*DIMC + lc0 + j*16] = acc[i][j][r] + bj[j];
    }
  }
}

// ---------------- fused QKV-projection + window attention ----------------
// 1 block = (window, 4-head group), 4 waves, wave owns 1 head.
// x-tile (64x384) staged once; each wave streams its own head's qkv-weight
// slices through a PRIVATE LDS double-buffer with counted vmcnt(4) waits --
// no barriers in the K-loop (cross-wave independence). Q/K/V never touch HBM.
// LDS: xa 48K + wl 32K + qk 32K + vt 16K = 128 KB -> 1 block/CU.
__global__ __launch_bounds__(256, 1) void qkv_attn(
    const u16* __restrict__ Xb, const u16* __restrict__ Wq,
    const float* __restrict__ qkvb, const float* __restrict__ biasT,
    const float* __restrict__ mask, u16* __restrict__ AO)
{
  __shared__ u16 xa[64*384];        // x rows [64][384], low-3-bit 16B-unit XOR swizzle
  __shared__ u16 wl[4][2][2048];    // per-wave W dbuf [32 n][64 k], gemm_bt swizzle
  __shared__ u16 qk[4][4096];       // per-wave [q 64x32 | k 64x32], overlaid by P
  __shared__ u16 vt[4][2048];       // per-wave vT [32 dims][64 toks] (swizzled)

  const int bid = blockIdx.x;
  const int L = (bid & 7) * ((NWIN*3) >> 3) + (bid >> 3);  // XCD-chunked swizzle:
  const int w = L / 3, hg = L % 3;                         // window's 3 blocks share L2
  const int tid = threadIdx.x, wv = tid >> 6, ln = tid & 63;
  const int cl = ln & 15, g = ln >> 4;
  const size_t rb = (size_t)w * SEQ;
  const int h = hg*4 + wv;                                 // global head of this wave
  const f32x4 zero4 = {0.f,0.f,0.f,0.f};
  const float scale = 0.17677669529663687f;                // 32^-0.5 (folded into Q)

  // qkv bias fragments (issued before the barrier so its vmcnt(0) drain covers them)
  float bb[3][2];
  #pragma unroll
  for(int p=0;p<3;p++)
    #pragma unroll
    for(int j=0;j<2;j++) bb[p][j] = qkvb[p*384 + h*32 + j*16 + cl];

  // stage x rows [rb, rb+64) x 384 into xa (pre-swizzled source, linear dest)
  #pragma unroll
  for(int c=0;c<12;c++){
    int un = c*256 + tid;                 // phys 16B-unit 0..3071
    int row = un / 48, up = un % 48;      // 48 units per row
    int u = (up & 0x38) | ((up ^ row) & 7);
    gload_lds16(Xb + (rb + row)*DIMC + u*8, &xa[(c*256 + wv*64)*8]);
  }
  __syncthreads();                        // only barrier: xa is cross-wave shared

  // per-wave W stage: step s (pass p = s/6, k-tile kt = s%6) into buffer b
  auto stageW = [&](int s, int b){
    const int p = s/6, kt = s - p*6;
    const size_t nb = (size_t)(p*384 + h*32);
    #pragma unroll
    for(int c=0;c<4;c++){
      int un = c*64 + ln;                 // 0..255 units of the 32x64 tile
      int row = un >> 3;
      int u = (un & 7) ^ (row & 7);
      gload_lds16(Wq + (nb + row)*DIMC + kt*64 + u*8, &wl[wv][b][c*512]);
    }
  };

  f32x4 acc[4][2];
  stageW(0, 0);
  #pragma unroll
  for(int s=0;s<18;s++){
    if ((s % 6) == 0){
      #pragma unroll
      for(int i=0;i<4;i++){ acc[i][0] = zero4; acc[i][1] = zero4; }
    }
    if (s < 17){
      // guard: prior-step ds_reads of the buffer we're about to overwrite must
      // complete before the DMA lands (compiler can't see gload_lds->LDS dep)
      asm volatile("s_waitcnt lgkmcnt(0)" ::: "memory");
      __builtin_amdgcn_sched_barrier(0);
      stageW(s+1, (s+1)&1);
      asm volatile("s_waitcnt vmcnt(4)" ::: "memory");   // W(s) landed, W(s+1) in flight
    } else {
      asm volatile("s_waitcnt vmcnt(0)" ::: "memory");
    }
    __builtin_amdgcn_sched_barrier(0);
    const int kt = s % 6, b = s & 1;
    #pragma unroll
    for(int ks=0;ks<2;ks++){
      bf16x8 af[4], bw[2];
      #pragma unroll
      for(int i=0;i<4;i++){
        int row = i*16 + cl;
        int ug = kt*8 + ks*4 + g;                        // global k unit 0..47
        int pu = (ug & 0x38) | ((ug ^ row) & 7);
        af[i] = *(const bf16x8*)&xa[row*384 + pu*8];
      }
      #pragma unroll
      for(int j=0;j<2;j++){
        int row = j*16 + cl;
        int u = (ks*4 + g) ^ (row & 7);
        bw[j] = *(const bf16x8*)&wl[wv][b][row*64 + u*8];
      }
      #pragma unroll
      for(int i=0;i<4;i++)
        #pragma unroll
        for(int j=0;j<2;j++)
          acc[i][j] = mfma_bf16(af[i], bw[j], acc[i][j]);
    }
    if (s == 5){                                         // Q epilogue (scale folded)
      #pragma unroll
      for(int i=0;i<4;i++)
        #pragma unroll
        for(int j=0;j<2;j++)
          #pragma unroll
          for(int r=0;r<4;r++){
            int tok = i*16 + g*4 + r;
            qk[wv][tok*32 + j*16 + cl] = f2bf((acc[i][j][r] + bb[0][j]) * scale);
          }
    }
    if (s == 11){                                        // K epilogue
      #pragma unroll
      for(int i=0;i<4;i++)
        #pragma unroll
        for(int j=0;j<2;j++)
          #pragma unroll
          for(int r=0;r<4;r++){
            int tok = i*16 + g*4 + r;
            qk[wv][2048 + tok*32 + j*16 + cl] = f2bf(acc[i][j][r] + bb[1][j]);
          }
    }
    if (s == 17){                                        // V epilogue -> vT (swizzled)
      #pragma unroll
      for(int i=0;i<4;i++)
        #pragma unroll
        for(int j=0;j<2;j++)
          #pragma unroll
          for(int r=0;r<4;r++){
            int tok = i*16 + g*4 + r, dh = j*16 + cl;
            vt[wv][dh*64 + (((tok>>3) ^ (dh&7))*8) + (tok&7)] =
                f2bf(acc[i][j][r] + bb[2][j]);
          }
    }
  }

  // ---- attention (wave-private; identical to verified layout) ----
  u16* ph = qk[wv];
  const u16* pv = vt[wv];

  bf16x8 aq[4], bk[4];
  #pragma unroll
  for(int i=0;i<4;i++) aq[i] = *(const bf16x8*)&ph[(i*16 + cl)*32 + g*8];
  #pragma unroll
  for(int j=0;j<4;j++) bk[j] = *(const bf16x8*)&ph[2048 + (j*16 + cl)*32 + g*8];
  f32x4 S[4][4];
  #pragma unroll
  for(int i=0;i<4;i++)
    #pragma unroll
    for(int j=0;j<4;j++)
      S[i][j] = mfma_bf16(aq[i], bk[j], zero4);   // K=32: one k-step

  float l[4][4];
  #pragma unroll
  for(int i=0;i<4;i++){
    #pragma unroll
    for(int r=0;r<4;r++){
      int row = i*16 + g*4 + r;
      float v0[4];
      #pragma unroll
      for(int j=0;j<4;j++){
        int col2 = j*16 + cl;
        v0[j] = S[i][j][r] + biasT[h*4096 + row*64 + col2]
                           + mask[(size_t)w*4096 + row*64 + col2];
      }
      float mx = fmaxf(fmaxf(v0[0],v0[1]), fmaxf(v0[2],v0[3]));
      #pragma unroll
      for(int s=1;s<16;s<<=1) mx = fmaxf(mx, __shfl_xor(mx, s));
      float sm = 0.f;
      #pragma unroll
      for(int j=0;j<4;j++){ v0[j] = __expf(v0[j]-mx); sm += v0[j]; }
      #pragma unroll
      for(int s=1;s<16;s<<=1) sm += __shfl_xor(sm, s);
      l[i][r] = sm;
      // P (unnormalized) -> LDS over q|k slot, A-layout rows of 64 cols, swizzled
      #pragma unroll
      for(int j=0;j<4;j++){
        int col2 = j*16 + cl;
        ph[row*64 + (((col2>>3) ^ (row&7))*8) + (col2&7)] = f2bf(v0[j]);
      }
    }
  }
  // O = P @ V  (64x64 @ 64x32, 2 k-steps)
  f32x4 O[4][2];
  #pragma unroll
  for(int i=0;i<4;i++){ O[i][0] = zero4; O[i][1] = zero4; }
  #pragma unroll
  for(int ks=0;ks<2;ks++){
    bf16x8 ap[4], bv[2];
    #pragma unroll
    for(int i=0;i<4;i++){
      int m = i*16 + cl;
      ap[i] = *(const bf16x8*)&ph[m*64 + (((ks*4+g) ^ (m&7))*8)];
    }
    #pragma unroll
    for(int j=0;j<2;j++){
      int n = j*16 + cl;
      bv[j] = *(const bf16x8*)&pv[n*64 + (((ks*4+g) ^ (n&7))*8)];
    }
    #pragma unroll
    for(int i=0;i<4;i++)
      #pragma unroll
      for(int j=0;j<2;j++)
        O[i][j] = mfma_bf16(ap[i], bv[j], O[i][j]);
  }
  #pragma unroll
  for(int i=0;i<4;i++){
    #pragma unroll
    for(int r=0;r<4;r++){
      float inv = 1.0f / l[i][r];
      size_t orow = (rb + i*16 + g*4 + r)*DIMC + h*HDIM;
      AO[orow + cl]      = f2bf(O[i][0][r]*inv);
      AO[orow + 16 + cl] = f2bf(O[i][1][r]*inv);
    }
  }
}

// ---------------- launch ----------------
extern "C" void kernel_launch(void* const* d_in, const int* in_sizes, int n_in,
                              void* d_out, int out_size, void* d_ws, size_t ws_size,
                              hipStream_t stream) {
  const float* x      = (const float*)d_in[0];
  const float* mask   = (const float*)d_in[1];
  const float* qkv_w  = (const float*)d_in[2];
  const float* qkv_b  = (const float*)d_in[3];
  const float* rpb    = (const float*)d_in[4];
  const float* proj_w = (const float*)d_in[5];
  const float* proj_b = (const float*)d_in[6];
  const int*   rpi    = (const int*)d_in[7];

  // ws layout (u16 units): [x_bf16 | attn_out | wqT | wpT] then biasT (f32)
  u16* xb  = (u16*)d_ws;                        // NROWS*DIMC
  u16* ao  = xb + (size_t)NROWS*DIMC;           // NROWS*DIMC (attn-out; NOT aliasing xb:
                                                //  sibling blocks still read x)
  u16* wqT = ao + (size_t)NROWS*DIMC;
  u16* wpT = wqT + (size_t)NQKV*DIMC;
  float* biasT = (float*)(wpT + (size_t)DIMC*DIMC);

  prep_x<<<(NROWS*(size_t)DIMC)/(256*8), 256, 0, stream>>>(x, xb);
  prep_w<<<(NQKV*DIMC + DIMC*DIMC + NHEAD*4096)/256, 256, 0, stream>>>(
      qkv_w, proj_w, rpb, rpi, wqT, wpT, biasT);
  qkv_attn<<<NWIN*3, 256, 0, stream>>>(xb, wqT, qkv_b, biasT, mask, ao);
  gemm_bt<3,1><<<2048*3, 256, 0, stream>>>(ao, wpT, proj_b, nullptr, nullptr, nullptr,
                                           (float*)d_out);
}